// Round 4
// baseline (1029.030 us; speedup 1.0000x reference)
//
#include <hip/hip_runtime.h>
#include <math.h>

#define DEV_INLINE __device__ __forceinline__

typedef __attribute__((ext_vector_type(8))) short short8v;
typedef __attribute__((ext_vector_type(4))) short short4v;
typedef __attribute__((ext_vector_type(4))) float float4v;

// fp32 -> bf16 round-to-nearest-even (finite data only)
DEV_INLINE unsigned short f2bf_rtn(float f) {
  unsigned u = __float_as_uint(f);
  u += 0x7FFFu + ((u >> 16) & 1u);
  return (unsigned short)(u >> 16);
}
DEV_INLINE float bf2f(unsigned short s) { return __uint_as_float(((unsigned)s) << 16); }

// LDS swizzle: [row][32 shorts], 16B k-oct XORed with (row>>1)&3.
// chunk(row,oct) = (4*row + oct^((row>>1)&3)) mod 8 covers all 8 bank-chunks
// exactly twice over any 16 consecutive rows -> 2-way (free) on b128 frag
// reads; stage writes stay uniform. (Old row&3 variant was 4-way!)
DEV_INLINE int soff(int row, int oct) {
  return row * 32 + (((oct ^ (row >> 1)) & 3) << 3);
}

// ---------------------------------------------------------------------------
// Pre-pass: all three weight matrices -> transposed bf16 hi/lo planes.
// ---------------------------------------------------------------------------
__global__ void conv_w_all(const float* __restrict__ W0, const float* __restrict__ W1,
                           const float* __restrict__ W2, short* __restrict__ w0h,
                           short* __restrict__ w0l, short* __restrict__ w1h,
                           short* __restrict__ w1l, short* __restrict__ w2h,
                           short* __restrict__ w2l) {
  const int S0 = 256 * 192, S1 = 192 * 192, S2 = 192 * 40;
  int idx = blockIdx.x * 256 + threadIdx.x;
  const float* W; short *Wh, *Wl; int K, N;
  if (idx < S0) { W = W0; Wh = w0h; Wl = w0l; K = 256; N = 192; }
  else if (idx < S0 + S1) { idx -= S0; W = W1; Wh = w1h; Wl = w1l; K = 192; N = 192; }
  else if (idx < S0 + S1 + S2) { idx -= S0 + S1; W = W2; Wh = w2h; Wl = w2l; K = 192; N = 40; }
  else return;
  int n = idx / K, k = idx - n * K;
  float w = W[(size_t)k * N + n];
  unsigned short h = f2bf_rtn(w);
  Wh[idx] = (short)h;
  Wl[idx] = (short)f2bf_rtn(w - bf2f(h));
}

// ---------------------------------------------------------------------------
// Pre-pass: CSR offsets from all three sorted dst arrays.
// ---------------------------------------------------------------------------
__global__ void csr_all(const int* __restrict__ d0, const int* __restrict__ d1,
                        const int* __restrict__ d2, int* __restrict__ o0,
                        int* __restrict__ o1, int* __restrict__ o2,
                        int E0, int E1, int E2, int n1, int n2, int n3) {
  int i = blockIdx.x * 256 + threadIdx.x;
  const int* dst; int* off; int E, nd;
  if (i < E0) { dst = d0; off = o0; E = E0; nd = n1; }
  else if (i < E0 + E1) { i -= E0; dst = d1; off = o1; E = E1; nd = n2; }
  else if (i < E0 + E1 + E2) { i -= E0 + E1; dst = d2; off = o2; E = E2; nd = n3; }
  else return;
  int d = dst[i];
  int p = (i == 0) ? -1 : dst[i - 1];
  for (int q = p + 1; q <= d; ++q) off[q] = i;
  if (i == E - 1)
    for (int q = d + 1; q <= nd; ++q) off[q] = E;
}

// ---------------------------------------------------------------------------
// Full-width MFMA GEMM (bf16 3-term hi/lo, fp32-accurate) + fused el/er.
// BM=128, BN=NT*16, BK=32, 256 thr.  SPLIT: A given as pre-split bf16 planes
// (from agg epilogue) -> no inline conversion.  el/er stored stride ELS.
// ---------------------------------------------------------------------------
template <int NT, int H, int ELS, bool SPLIT>
__global__ __launch_bounds__(256, 4) void gemm_fused(
    const float* __restrict__ A, const short* __restrict__ Ah,
    const short* __restrict__ Al, const short* __restrict__ Bth,
    const short* __restrict__ Btl, const float* __restrict__ al,
    const float* __restrict__ ar, float* __restrict__ C,
    float* __restrict__ el, float* __restrict__ er,
    int M, int N, int K, int n_dst) {
  constexpr int BN = NT * 16;
  constexpr int BREP = (BN + 63) / 64;
  constexpr int TPH = NT / H;
  __shared__ short As_h[128 * 32], As_l[128 * 32];
  __shared__ short Bs_h[BN * 32], Bs_l[BN * 32];
  const int tid = threadIdx.x;
  const int w = tid >> 6, lane = tid & 63;
  const int quad = lane >> 4, l16 = lane & 15;
  const int m0 = blockIdx.x * 128;

  float4v acc[2][NT];
#pragma unroll
  for (int mt = 0; mt < 2; ++mt)
#pragma unroll
    for (int nt = 0; nt < NT; ++nt)
#pragma unroll
      for (int r = 0; r < 4; ++r) acc[mt][nt][r] = 0.f;

  const int sr = tid >> 2;   // stage row 0..63
  const int oct = tid & 3;   // k-oct 0..3

  for (int k0 = 0; k0 < K; k0 += 32) {
    // ---- global loads (before barrier) ----
    short8v ah_reg[2], al_reg[2];
    float4 a0[2], a1[2];
    if (SPLIT) {
#pragma unroll
      for (int p = 0; p < 2; ++p) {
        int gr = m0 + sr + p * 64;
        if (gr < M) {
          ah_reg[p] = *(const short8v*)(Ah + (size_t)gr * K + k0 + oct * 8);
          al_reg[p] = *(const short8v*)(Al + (size_t)gr * K + k0 + oct * 8);
        } else {
#pragma unroll
          for (int j = 0; j < 8; ++j) { ah_reg[p][j] = 0; al_reg[p][j] = 0; }
        }
      }
    } else {
#pragma unroll
      for (int p = 0; p < 2; ++p) {
        int gr = m0 + sr + p * 64;
        if (gr < M) {
          const float* ap = A + (size_t)gr * K + k0 + oct * 8;
          a0[p] = *(const float4*)ap;
          a1[p] = *(const float4*)(ap + 4);
        } else {
          a0[p] = make_float4(0.f, 0.f, 0.f, 0.f);
          a1[p] = a0[p];
        }
      }
    }
    short8v bh[BREP], bl[BREP];
#pragma unroll
    for (int q = 0; q < BREP; ++q) {
      int n = sr + q * 64;
      if (n < BN) {
        if (n < N) {
          bh[q] = *(const short8v*)(Bth + (size_t)n * K + k0 + oct * 8);
          bl[q] = *(const short8v*)(Btl + (size_t)n * K + k0 + oct * 8);
        } else {
#pragma unroll
          for (int j = 0; j < 8; ++j) { bh[q][j] = 0; bl[q][j] = 0; }
        }
      }
    }
    __syncthreads();
    // ---- stage ----
#pragma unroll
    for (int p = 0; p < 2; ++p) {
      int r = sr + p * 64;
      short8v hv, lv;
      if (SPLIT) {
        hv = ah_reg[p];
        lv = al_reg[p];
      } else {
        float vs[8] = {a0[p].x, a0[p].y, a0[p].z, a0[p].w,
                       a1[p].x, a1[p].y, a1[p].z, a1[p].w};
#pragma unroll
        for (int j = 0; j < 8; ++j) {
          unsigned short h = f2bf_rtn(vs[j]);
          hv[j] = (short)h;
          lv[j] = (short)f2bf_rtn(vs[j] - bf2f(h));
        }
      }
      *(short8v*)(As_h + soff(r, oct)) = hv;
      *(short8v*)(As_l + soff(r, oct)) = lv;
    }
#pragma unroll
    for (int q = 0; q < BREP; ++q) {
      int n = sr + q * 64;
      if (n < BN) {
        *(short8v*)(Bs_h + soff(n, oct)) = bh[q];
        *(short8v*)(Bs_l + soff(n, oct)) = bl[q];
      }
    }
    __syncthreads();
    // ---- fragments + MFMA ----
    short8v afh[2], afl[2];
#pragma unroll
    for (int mt = 0; mt < 2; ++mt) {
      int row = w * 32 + mt * 16 + l16;
      afh[mt] = *(const short8v*)(As_h + soff(row, quad));
      afl[mt] = *(const short8v*)(As_l + soff(row, quad));
    }
#pragma unroll
    for (int nt = 0; nt < NT; ++nt) {
      int col = nt * 16 + l16;
      short8v bfh = *(const short8v*)(Bs_h + soff(col, quad));
      short8v bfl = *(const short8v*)(Bs_l + soff(col, quad));
#pragma unroll
      for (int mt = 0; mt < 2; ++mt) {
        acc[mt][nt] = __builtin_amdgcn_mfma_f32_16x16x32_bf16(afh[mt], bfh, acc[mt][nt], 0, 0, 0);
        acc[mt][nt] = __builtin_amdgcn_mfma_f32_16x16x32_bf16(afh[mt], bfl, acc[mt][nt], 0, 0, 0);
        acc[mt][nt] = __builtin_amdgcn_mfma_f32_16x16x32_bf16(afl[mt], bfh, acc[mt][nt], 0, 0, 0);
      }
    }
  }

  // ---- epilogue: C store + fused el/er ----
  float av[NT], rv[NT];
#pragma unroll
  for (int nt = 0; nt < NT; ++nt) {
    int col = nt * 16 + l16;
    av[nt] = (col < N) ? al[col] : 0.f;
    rv[nt] = (col < N) ? ar[col] : 0.f;
  }
#pragma unroll
  for (int mt = 0; mt < 2; ++mt)
#pragma unroll
    for (int r = 0; r < 4; ++r) {
      int gm = m0 + w * 32 + mt * 16 + quad * 4 + r;
      if (gm >= M) continue;
      float pl[H], pr[H];
#pragma unroll
      for (int h = 0; h < H; ++h) { pl[h] = 0.f; pr[h] = 0.f; }
#pragma unroll
      for (int nt = 0; nt < NT; ++nt) {
        int h = nt / TPH;
        pl[h] = fmaf(acc[mt][nt][r], av[nt], pl[h]);
        pr[h] = fmaf(acc[mt][nt][r], rv[nt], pr[h]);
      }
#pragma unroll
      for (int h = 0; h < H; ++h) {
#pragma unroll
        for (int o = 8; o >= 1; o >>= 1) {
          pl[h] += __shfl_xor(pl[h], o, 16);
          pr[h] += __shfl_xor(pr[h], o, 16);
        }
      }
      if (l16 == 0) {
#pragma unroll
        for (int h = 0; h < H; ++h) {
          el[(size_t)gm * ELS + h] = pl[h];
          if (gm < n_dst) er[(size_t)gm * ELS + h] = pr[h];
        }
      }
#pragma unroll
      for (int nt = 0; nt < NT; ++nt) {
        int col = nt * 16 + l16;
        if (col < N) C[(size_t)gm * N + col] = acc[mt][nt][r];
      }
    }
}

// ---------------------------------------------------------------------------
// Aggregation v3: 16-lane group per dst node, CSR ranges, max-free softmax.
// Depth-3 row-gather pipeline (h0/h1/h2) -> ~9 b128 loads in flight/group.
// SPLIT_OUT: emit bf16 hi/lo planes (pre-split A for next gemm).
// ---------------------------------------------------------------------------
template <int H, int D, int ELS, bool RELU, bool SPLIT_OUT>
__global__ __launch_bounds__(256) void agg3_kernel(
    const float* __restrict__ hsrc, const float* __restrict__ el,
    const float* __restrict__ er, const int* __restrict__ src,
    const int* __restrict__ off, float* __restrict__ outf,
    short* __restrict__ outh, short* __restrict__ outl, int n_dst) {
  constexpr int F = H * D;
  constexpr int NP = (F + 63) / 64;
  __shared__ float wbuf[16][16][H];
  __shared__ int sbuf[16][16];
  const int g = threadIdx.x >> 4, l = threadIdx.x & 15;
  const int d = blockIdx.x * 16 + g;
  if (d >= n_dst) return;
  const int lo = off[d], hi = off[d + 1];

  if (hi <= lo) {
#pragma unroll
    for (int p = 0; p < NP; ++p) {
      int c4 = (p * 16 + l) * 4;
      if (c4 < F) {
        if (SPLIT_OUT) {
          short4v z;
#pragma unroll
          for (int j = 0; j < 4; ++j) z[j] = 0;
          *(short4v*)(outh + (size_t)d * F + c4) = z;
          *(short4v*)(outl + (size_t)d * F + c4) = z;
        } else {
          *(float4*)(outf + (size_t)d * F + c4) = make_float4(0.f, 0.f, 0.f, 0.f);
        }
      }
    }
    return;
  }

  float erv[H], s_part[H];
  if (H == 3) {
    float4 t = *(const float4*)(er + (size_t)d * ELS);
    erv[0] = t.x;
    if (H > 1) { erv[1] = t.y; erv[2] = t.z; }
  } else {
    erv[0] = er[(size_t)d * ELS];
  }
#pragma unroll
  for (int h = 0; h < H; ++h) s_part[h] = 0.f;
  float4 acc[NP];
#pragma unroll
  for (int p = 0; p < NP; ++p) acc[p] = make_float4(0.f, 0.f, 0.f, 0.f);

  for (int base = lo; base < hi; base += 16) {
    const int i = base + l;
    const bool valid = i < hi;
    const int sid = valid ? src[i] : 0;
    sbuf[g][l] = sid;
    float evs[H];
    if (H == 3) {
      float4 t = valid ? *(const float4*)(el + (size_t)sid * ELS)
                       : make_float4(0.f, 0.f, 0.f, 0.f);
      evs[0] = t.x;
      if (H > 1) { evs[1] = t.y; evs[2] = t.z; }
    } else {
      evs[0] = valid ? el[(size_t)sid * ELS] : 0.f;
    }
#pragma unroll
    for (int h = 0; h < H; ++h) {
      float e = 0.f;
      if (valid) {
        e = evs[h] + erv[h];
        e = e > 0.f ? e : 0.2f * e;  // leaky_relu 0.2
        e = __expf(e);
      }
      s_part[h] += e;
      wbuf[g][l][h] = e;
    }

    const int cnt = min(16, hi - base);
    // depth-3 pipelined gather
    float4 h0[NP], h1[NP], h2[NP];
    const int sj0 = sbuf[g][0];
    const int sj1 = sbuf[g][cnt > 1 ? 1 : 0];
#pragma unroll
    for (int p = 0; p < NP; ++p) {
      int c4 = (p * 16 + l) * 4;
      if (c4 < F) {
        h0[p] = *(const float4*)(hsrc + (size_t)sj0 * F + c4);
        h1[p] = *(const float4*)(hsrc + (size_t)sj1 * F + c4);
      } else {
        h0[p] = make_float4(0.f, 0.f, 0.f, 0.f);
        h1[p] = h0[p];
      }
    }
    for (int ei = 0; ei < cnt; ++ei) {
      if (ei + 2 < cnt) {
        const int sj2 = sbuf[g][ei + 2];
#pragma unroll
        for (int p = 0; p < NP; ++p) {
          int c4 = (p * 16 + l) * 4;
          h2[p] = (c4 < F) ? *(const float4*)(hsrc + (size_t)sj2 * F + c4)
                           : make_float4(0.f, 0.f, 0.f, 0.f);
        }
      }
#pragma unroll
      for (int p = 0; p < NP; ++p) {
        int c4 = (p * 16 + l) * 4;
        float wc = wbuf[g][ei][c4 / D];  // same addr across lanes: broadcast
        acc[p].x = fmaf(wc, h0[p].x, acc[p].x);
        acc[p].y = fmaf(wc, h0[p].y, acc[p].y);
        acc[p].z = fmaf(wc, h0[p].z, acc[p].z);
        acc[p].w = fmaf(wc, h0[p].w, acc[p].w);
      }
#pragma unroll
      for (int p = 0; p < NP; ++p) { h0[p] = h1[p]; h1[p] = h2[p]; }
    }
  }

#pragma unroll
  for (int h = 0; h < H; ++h)
#pragma unroll
    for (int o = 8; o >= 1; o >>= 1) s_part[h] += __shfl_xor(s_part[h], o, 16);

#pragma unroll
  for (int p = 0; p < NP; ++p) {
    int c4 = (p * 16 + l) * 4;
    if (c4 < F) {
      float inv = 1.f / s_part[c4 / D];
      float4 o;
      o.x = acc[p].x * inv; o.y = acc[p].y * inv;
      o.z = acc[p].z * inv; o.w = acc[p].w * inv;
      if (RELU) {
        o.x = fmaxf(o.x, 0.f); o.y = fmaxf(o.y, 0.f);
        o.z = fmaxf(o.z, 0.f); o.w = fmaxf(o.w, 0.f);
      }
      if (SPLIT_OUT) {
        float vs[4] = {o.x, o.y, o.z, o.w};
        short4v sh, sl;
#pragma unroll
        for (int j = 0; j < 4; ++j) {
          unsigned short hh = f2bf_rtn(vs[j]);
          sh[j] = (short)hh;
          sl[j] = (short)f2bf_rtn(vs[j] - bf2f(hh));
        }
        *(short4v*)(outh + (size_t)d * F + c4) = sh;
        *(short4v*)(outl + (size_t)d * F + c4) = sl;
      } else {
        *(float4*)(outf + (size_t)d * F + c4) = o;
      }
    }
  }
}

// ---------------------------------------------------------------------------
extern "C" void kernel_launch(void* const* d_in, const int* in_sizes, int n_in,
                              void* d_out, int out_size, void* d_ws, size_t ws_size,
                              hipStream_t stream) {
  const float* x   = (const float*)d_in[0];
  const int* src0  = (const int*)d_in[1];
  const int* dst0  = (const int*)d_in[2];
  const int* src1  = (const int*)d_in[3];
  const int* dst1  = (const int*)d_in[4];
  const int* src2  = (const int*)d_in[5];
  const int* dst2  = (const int*)d_in[6];
  const float* W0  = (const float*)d_in[7];
  const float* al0 = (const float*)d_in[8];
  const float* ar0 = (const float*)d_in[9];
  const float* W1  = (const float*)d_in[10];
  const float* al1 = (const float*)d_in[11];
  const float* ar1 = (const float*)d_in[12];
  const float* W2  = (const float*)d_in[13];
  const float* al2 = (const float*)d_in[14];
  const float* ar2 = (const float*)d_in[15];

  const int N0 = 200000, N1 = 100000, N2 = 50000, N3 = 25000;
  const int E0 = in_sizes[1], E1 = in_sizes[3], E2 = in_sizes[5];
  const int Fin = 256, F = 192, C = 40;

  // ---- workspace layout ----
  float* ws     = (float*)d_ws;
  float* h_buf  = ws;                          // 200000*192 fp32 (gemm C)
  float* el_buf = h_buf + (size_t)N0 * F;      // 200000*4 (stride-4 padded)
  float* er_buf = el_buf + (size_t)N0 * 4;     // 100000*4
  short* o_hi   = (short*)(er_buf + (size_t)N1 * 4);  // 100000*192 bf16 planes
  short* o_lo   = o_hi + (size_t)N1 * F;
  short* w0h    = o_lo + (size_t)N1 * F;
  short* w0l    = w0h + 192 * 256;
  short* w1h    = w0l + 192 * 256;
  short* w1l    = w1h + 192 * 192;
  short* w2h    = w1l + 192 * 192;
  short* w2l    = w2h + 40 * 192;
  int*   off0   = (int*)(w2l + 40 * 192);
  int*   off1   = off0 + (N1 + 1);
  int*   off2   = off1 + (N2 + 1);

  dim3 blk(256);

  // ---- pre-passes ----
  const int WTOT = 256 * 192 + 192 * 192 + 192 * 40;
  conv_w_all<<<dim3((WTOT + 255) / 256), blk, 0, stream>>>(W0, W1, W2, w0h, w0l, w1h, w1l, w2h, w2l);
  const int ETOT = E0 + E1 + E2;
  csr_all<<<dim3((ETOT + 255) / 256), blk, 0, stream>>>(dst0, dst1, dst2, off0, off1, off2,
                                                        E0, E1, E2, N1, N2, N3);

  // ---- Layer 0 (A = x fp32, inline split) ----
  gemm_fused<12, 3, 4, false><<<dim3((N0 + 127) / 128), blk, 0, stream>>>(
      x, nullptr, nullptr, w0h, w0l, al0, ar0, h_buf, el_buf, er_buf, N0, F, Fin, N1);
  agg3_kernel<3, 64, 4, true, true><<<dim3((N1 + 15) / 16), blk, 0, stream>>>(
      h_buf, el_buf, er_buf, src0, off0, nullptr, o_hi, o_lo, N1);

  // ---- Layer 1 (A = pre-split planes) ----
  gemm_fused<12, 3, 4, true><<<dim3((N1 + 127) / 128), blk, 0, stream>>>(
      nullptr, o_hi, o_lo, w1h, w1l, al1, ar1, h_buf, el_buf, er_buf, N1, F, F, N2);
  agg3_kernel<3, 64, 4, true, true><<<dim3((N2 + 15) / 16), blk, 0, stream>>>(
      h_buf, el_buf, er_buf, src1, off1, nullptr, o_hi, o_lo, N2);

  // ---- Layer 2 (N=40, H=1, pre-split A, fp32 out, no relu) ----
  gemm_fused<3, 1, 1, true><<<dim3((N2 + 127) / 128), blk, 0, stream>>>(
      nullptr, o_hi, o_lo, w2h, w2l, al2, ar2, h_buf, el_buf, er_buf, N2, C, F, N3);
  agg3_kernel<1, 40, 1, false, false><<<dim3((N3 + 15) / 16), blk, 0, stream>>>(
      h_buf, el_buf, er_buf, src2, off2, (float*)d_out, nullptr, nullptr, N3);
}

// Round 5
// 644.677 us; speedup vs baseline: 1.5962x; 1.5962x over previous
//
#include <hip/hip_runtime.h>
#include <math.h>

#define DEV_INLINE __device__ __forceinline__

typedef __attribute__((ext_vector_type(8))) short short8v;
typedef __attribute__((ext_vector_type(4))) short short4v;
typedef __attribute__((ext_vector_type(4))) float float4v;

// fp32 -> bf16 round-to-nearest-even (finite data only)
DEV_INLINE unsigned short f2bf_rtn(float f) {
  unsigned u = __float_as_uint(f);
  u += 0x7FFFu + ((u >> 16) & 1u);
  return (unsigned short)(u >> 16);
}
DEV_INLINE float bf2f(unsigned short s) { return __uint_as_float(((unsigned)s) << 16); }

// LDS swizzle: [row][32 shorts], 16B k-oct XORed with (row>>1)&3.
// chunk(row,oct) = (4*row + oct^((row>>1)&3)) mod 8 covers all 8 bank-chunks
// exactly twice over any 16 consecutive rows -> 2-way (free) on b128 frag
// reads; stage writes stay uniform. (Verified: SQ_LDS_BANK_CONFLICT = 0.)
DEV_INLINE int soff(int row, int oct) {
  return row * 32 + (((oct ^ (row >> 1)) & 3) << 3);
}

// ---------------------------------------------------------------------------
// Pre-pass: all three weight matrices -> transposed bf16 hi/lo planes.
// ---------------------------------------------------------------------------
__global__ void conv_w_all(const float* __restrict__ W0, const float* __restrict__ W1,
                           const float* __restrict__ W2, short* __restrict__ w0h,
                           short* __restrict__ w0l, short* __restrict__ w1h,
                           short* __restrict__ w1l, short* __restrict__ w2h,
                           short* __restrict__ w2l) {
  const int S0 = 256 * 192, S1 = 192 * 192, S2 = 192 * 40;
  int idx = blockIdx.x * 256 + threadIdx.x;
  const float* W; short *Wh, *Wl; int K, N;
  if (idx < S0) { W = W0; Wh = w0h; Wl = w0l; K = 256; N = 192; }
  else if (idx < S0 + S1) { idx -= S0; W = W1; Wh = w1h; Wl = w1l; K = 192; N = 192; }
  else if (idx < S0 + S1 + S2) { idx -= S0 + S1; W = W2; Wh = w2h; Wl = w2l; K = 192; N = 40; }
  else return;
  int n = idx / K, k = idx - n * K;
  float w = W[(size_t)k * N + n];
  unsigned short h = f2bf_rtn(w);
  Wh[idx] = (short)h;
  Wl[idx] = (short)f2bf_rtn(w - bf2f(h));
}

// ---------------------------------------------------------------------------
// Pre-pass: CSR offsets from all three sorted dst arrays.
// ---------------------------------------------------------------------------
__global__ void csr_all(const int* __restrict__ d0, const int* __restrict__ d1,
                        const int* __restrict__ d2, int* __restrict__ o0,
                        int* __restrict__ o1, int* __restrict__ o2,
                        int E0, int E1, int E2, int n1, int n2, int n3) {
  int i = blockIdx.x * 256 + threadIdx.x;
  const int* dst; int* off; int E, nd;
  if (i < E0) { dst = d0; off = o0; E = E0; nd = n1; }
  else if (i < E0 + E1) { i -= E0; dst = d1; off = o1; E = E1; nd = n2; }
  else if (i < E0 + E1 + E2) { i -= E0 + E1; dst = d2; off = o2; E = E2; nd = n3; }
  else return;
  int d = dst[i];
  int p = (i == 0) ? -1 : dst[i - 1];
  for (int q = p + 1; q <= d; ++q) off[q] = i;
  if (i == E - 1)
    for (int q = d + 1; q <= nd; ++q) off[q] = E;
}

// ---------------------------------------------------------------------------
// Full-width MFMA GEMM (bf16 3-term hi/lo, fp32-accurate) + fused el/er.
// BM=128, BN=NT*16, BK=32, 256 thr.  SPLIT: A given as pre-split bf16 planes.
// __launch_bounds__(256,2): 256 unified regs/wave -- fits the ~116 VGPR +
// 96 AGPR allocation.  (256,4) capped at 128 and spilled acc to scratch:
// WRITE_SIZE 154->804 MB, 3x slower.  Do not raise the min-waves arg.
// ---------------------------------------------------------------------------
template <int NT, int H, int ELS, bool SPLIT>
__global__ __launch_bounds__(256, 2) void gemm_fused(
    const float* __restrict__ A, const short* __restrict__ Ah,
    const short* __restrict__ Al, const short* __restrict__ Bth,
    const short* __restrict__ Btl, const float* __restrict__ al,
    const float* __restrict__ ar, float* __restrict__ C,
    float* __restrict__ el, float* __restrict__ er,
    int M, int N, int K, int n_dst) {
  constexpr int BN = NT * 16;
  constexpr int BREP = (BN + 63) / 64;
  constexpr int TPH = NT / H;
  __shared__ short As_h[128 * 32], As_l[128 * 32];
  __shared__ short Bs_h[BN * 32], Bs_l[BN * 32];
  const int tid = threadIdx.x;
  const int w = tid >> 6, lane = tid & 63;
  const int quad = lane >> 4, l16 = lane & 15;
  const int m0 = blockIdx.x * 128;

  float4v acc[2][NT];
#pragma unroll
  for (int mt = 0; mt < 2; ++mt)
#pragma unroll
    for (int nt = 0; nt < NT; ++nt)
#pragma unroll
      for (int r = 0; r < 4; ++r) acc[mt][nt][r] = 0.f;

  const int sr = tid >> 2;   // stage row 0..63
  const int oct = tid & 3;   // k-oct 0..3

  for (int k0 = 0; k0 < K; k0 += 32) {
    // ---- global loads (before barrier) ----
    short8v ah_reg[2], al_reg[2];
    float4 a0[2], a1[2];
    if (SPLIT) {
#pragma unroll
      for (int p = 0; p < 2; ++p) {
        int gr = m0 + sr + p * 64;
        if (gr < M) {
          ah_reg[p] = *(const short8v*)(Ah + (size_t)gr * K + k0 + oct * 8);
          al_reg[p] = *(const short8v*)(Al + (size_t)gr * K + k0 + oct * 8);
        } else {
#pragma unroll
          for (int j = 0; j < 8; ++j) { ah_reg[p][j] = 0; al_reg[p][j] = 0; }
        }
      }
    } else {
#pragma unroll
      for (int p = 0; p < 2; ++p) {
        int gr = m0 + sr + p * 64;
        if (gr < M) {
          const float* ap = A + (size_t)gr * K + k0 + oct * 8;
          a0[p] = *(const float4*)ap;
          a1[p] = *(const float4*)(ap + 4);
        } else {
          a0[p] = make_float4(0.f, 0.f, 0.f, 0.f);
          a1[p] = a0[p];
        }
      }
    }
    short8v bh[BREP], bl[BREP];
#pragma unroll
    for (int q = 0; q < BREP; ++q) {
      int n = sr + q * 64;
      if (n < BN) {
        if (n < N) {
          bh[q] = *(const short8v*)(Bth + (size_t)n * K + k0 + oct * 8);
          bl[q] = *(const short8v*)(Btl + (size_t)n * K + k0 + oct * 8);
        } else {
#pragma unroll
          for (int j = 0; j < 8; ++j) { bh[q][j] = 0; bl[q][j] = 0; }
        }
      }
    }
    __syncthreads();
    // ---- stage ----
#pragma unroll
    for (int p = 0; p < 2; ++p) {
      int r = sr + p * 64;
      short8v hv, lv;
      if (SPLIT) {
        hv = ah_reg[p];
        lv = al_reg[p];
      } else {
        float vs[8] = {a0[p].x, a0[p].y, a0[p].z, a0[p].w,
                       a1[p].x, a1[p].y, a1[p].z, a1[p].w};
#pragma unroll
        for (int j = 0; j < 8; ++j) {
          unsigned short h = f2bf_rtn(vs[j]);
          hv[j] = (short)h;
          lv[j] = (short)f2bf_rtn(vs[j] - bf2f(h));
        }
      }
      *(short8v*)(As_h + soff(r, oct)) = hv;
      *(short8v*)(As_l + soff(r, oct)) = lv;
    }
#pragma unroll
    for (int q = 0; q < BREP; ++q) {
      int n = sr + q * 64;
      if (n < BN) {
        *(short8v*)(Bs_h + soff(n, oct)) = bh[q];
        *(short8v*)(Bs_l + soff(n, oct)) = bl[q];
      }
    }
    __syncthreads();
    // ---- fragments + MFMA ----
    short8v afh[2], afl[2];
#pragma unroll
    for (int mt = 0; mt < 2; ++mt) {
      int row = w * 32 + mt * 16 + l16;
      afh[mt] = *(const short8v*)(As_h + soff(row, quad));
      afl[mt] = *(const short8v*)(As_l + soff(row, quad));
    }
#pragma unroll
    for (int nt = 0; nt < NT; ++nt) {
      int col = nt * 16 + l16;
      short8v bfh = *(const short8v*)(Bs_h + soff(col, quad));
      short8v bfl = *(const short8v*)(Bs_l + soff(col, quad));
#pragma unroll
      for (int mt = 0; mt < 2; ++mt) {
        acc[mt][nt] = __builtin_amdgcn_mfma_f32_16x16x32_bf16(afh[mt], bfh, acc[mt][nt], 0, 0, 0);
        acc[mt][nt] = __builtin_amdgcn_mfma_f32_16x16x32_bf16(afh[mt], bfl, acc[mt][nt], 0, 0, 0);
        acc[mt][nt] = __builtin_amdgcn_mfma_f32_16x16x32_bf16(afl[mt], bfh, acc[mt][nt], 0, 0, 0);
      }
    }
  }

  // ---- epilogue: C store + fused el/er ----
  float av[NT], rv[NT];
#pragma unroll
  for (int nt = 0; nt < NT; ++nt) {
    int col = nt * 16 + l16;
    av[nt] = (col < N) ? al[col] : 0.f;
    rv[nt] = (col < N) ? ar[col] : 0.f;
  }
#pragma unroll
  for (int mt = 0; mt < 2; ++mt)
#pragma unroll
    for (int r = 0; r < 4; ++r) {
      int gm = m0 + w * 32 + mt * 16 + quad * 4 + r;
      if (gm >= M) continue;
      float pl[H], pr[H];
#pragma unroll
      for (int h = 0; h < H; ++h) { pl[h] = 0.f; pr[h] = 0.f; }
#pragma unroll
      for (int nt = 0; nt < NT; ++nt) {
        int h = nt / TPH;
        pl[h] = fmaf(acc[mt][nt][r], av[nt], pl[h]);
        pr[h] = fmaf(acc[mt][nt][r], rv[nt], pr[h]);
      }
#pragma unroll
      for (int h = 0; h < H; ++h) {
#pragma unroll
        for (int o = 8; o >= 1; o >>= 1) {
          pl[h] += __shfl_xor(pl[h], o, 16);
          pr[h] += __shfl_xor(pr[h], o, 16);
        }
      }
      if (l16 == 0) {
#pragma unroll
        for (int h = 0; h < H; ++h) {
          el[(size_t)gm * ELS + h] = pl[h];
          if (gm < n_dst) er[(size_t)gm * ELS + h] = pr[h];
        }
      }
#pragma unroll
      for (int nt = 0; nt < NT; ++nt) {
        int col = nt * 16 + l16;
        if (col < N) C[(size_t)gm * N + col] = acc[mt][nt][r];
      }
    }
}

// ---------------------------------------------------------------------------
// Aggregation v3: 16-lane group per dst node, CSR ranges, max-free softmax.
// Depth-3 row-gather pipeline (h0/h1/h2) -> ~9 b128 loads in flight/group.
// SPLIT_OUT: emit bf16 hi/lo planes (pre-split A for next gemm).
// ---------------------------------------------------------------------------
template <int H, int D, int ELS, bool RELU, bool SPLIT_OUT>
__global__ __launch_bounds__(256) void agg3_kernel(
    const float* __restrict__ hsrc, const float* __restrict__ el,
    const float* __restrict__ er, const int* __restrict__ src,
    const int* __restrict__ off, float* __restrict__ outf,
    short* __restrict__ outh, short* __restrict__ outl, int n_dst) {
  constexpr int F = H * D;
  constexpr int NP = (F + 63) / 64;
  __shared__ float wbuf[16][16][H];
  __shared__ int sbuf[16][16];
  const int g = threadIdx.x >> 4, l = threadIdx.x & 15;
  const int d = blockIdx.x * 16 + g;
  if (d >= n_dst) return;
  const int lo = off[d], hi = off[d + 1];

  if (hi <= lo) {
#pragma unroll
    for (int p = 0; p < NP; ++p) {
      int c4 = (p * 16 + l) * 4;
      if (c4 < F) {
        if (SPLIT_OUT) {
          short4v z;
#pragma unroll
          for (int j = 0; j < 4; ++j) z[j] = 0;
          *(short4v*)(outh + (size_t)d * F + c4) = z;
          *(short4v*)(outl + (size_t)d * F + c4) = z;
        } else {
          *(float4*)(outf + (size_t)d * F + c4) = make_float4(0.f, 0.f, 0.f, 0.f);
        }
      }
    }
    return;
  }

  float erv[H], s_part[H];
  if (H == 3) {
    float4 t = *(const float4*)(er + (size_t)d * ELS);
    erv[0] = t.x;
    if (H > 1) { erv[1] = t.y; erv[2] = t.z; }
  } else {
    erv[0] = er[(size_t)d * ELS];
  }
#pragma unroll
  for (int h = 0; h < H; ++h) s_part[h] = 0.f;
  float4 acc[NP];
#pragma unroll
  for (int p = 0; p < NP; ++p) acc[p] = make_float4(0.f, 0.f, 0.f, 0.f);

  for (int base = lo; base < hi; base += 16) {
    const int i = base + l;
    const bool valid = i < hi;
    const int sid = valid ? src[i] : 0;
    sbuf[g][l] = sid;
    float evs[H];
    if (H == 3) {
      float4 t = valid ? *(const float4*)(el + (size_t)sid * ELS)
                       : make_float4(0.f, 0.f, 0.f, 0.f);
      evs[0] = t.x;
      if (H > 1) { evs[1] = t.y; evs[2] = t.z; }
    } else {
      evs[0] = valid ? el[(size_t)sid * ELS] : 0.f;
    }
#pragma unroll
    for (int h = 0; h < H; ++h) {
      float e = 0.f;
      if (valid) {
        e = evs[h] + erv[h];
        e = e > 0.f ? e : 0.2f * e;  // leaky_relu 0.2
        e = __expf(e);
      }
      s_part[h] += e;
      wbuf[g][l][h] = e;
    }

    const int cnt = min(16, hi - base);
    // depth-3 pipelined gather
    float4 h0[NP], h1[NP], h2[NP];
    const int sj0 = sbuf[g][0];
    const int sj1 = sbuf[g][cnt > 1 ? 1 : 0];
#pragma unroll
    for (int p = 0; p < NP; ++p) {
      int c4 = (p * 16 + l) * 4;
      if (c4 < F) {
        h0[p] = *(const float4*)(hsrc + (size_t)sj0 * F + c4);
        h1[p] = *(const float4*)(hsrc + (size_t)sj1 * F + c4);
      } else {
        h0[p] = make_float4(0.f, 0.f, 0.f, 0.f);
        h1[p] = h0[p];
      }
    }
    for (int ei = 0; ei < cnt; ++ei) {
      if (ei + 2 < cnt) {
        const int sj2 = sbuf[g][ei + 2];
#pragma unroll
        for (int p = 0; p < NP; ++p) {
          int c4 = (p * 16 + l) * 4;
          h2[p] = (c4 < F) ? *(const float4*)(hsrc + (size_t)sj2 * F + c4)
                           : make_float4(0.f, 0.f, 0.f, 0.f);
        }
      }
#pragma unroll
      for (int p = 0; p < NP; ++p) {
        int c4 = (p * 16 + l) * 4;
        float wc = wbuf[g][ei][c4 / D];  // same addr across lanes: broadcast
        acc[p].x = fmaf(wc, h0[p].x, acc[p].x);
        acc[p].y = fmaf(wc, h0[p].y, acc[p].y);
        acc[p].z = fmaf(wc, h0[p].z, acc[p].z);
        acc[p].w = fmaf(wc, h0[p].w, acc[p].w);
      }
#pragma unroll
      for (int p = 0; p < NP; ++p) { h0[p] = h1[p]; h1[p] = h2[p]; }
    }
  }

#pragma unroll
  for (int h = 0; h < H; ++h)
#pragma unroll
    for (int o = 8; o >= 1; o >>= 1) s_part[h] += __shfl_xor(s_part[h], o, 16);

#pragma unroll
  for (int p = 0; p < NP; ++p) {
    int c4 = (p * 16 + l) * 4;
    if (c4 < F) {
      float inv = 1.f / s_part[c4 / D];
      float4 o;
      o.x = acc[p].x * inv; o.y = acc[p].y * inv;
      o.z = acc[p].z * inv; o.w = acc[p].w * inv;
      if (RELU) {
        o.x = fmaxf(o.x, 0.f); o.y = fmaxf(o.y, 0.f);
        o.z = fmaxf(o.z, 0.f); o.w = fmaxf(o.w, 0.f);
      }
      if (SPLIT_OUT) {
        float vs[4] = {o.x, o.y, o.z, o.w};
        short4v sh, sl;
#pragma unroll
        for (int j = 0; j < 4; ++j) {
          unsigned short hh = f2bf_rtn(vs[j]);
          sh[j] = (short)hh;
          sl[j] = (short)f2bf_rtn(vs[j] - bf2f(hh));
        }
        *(short4v*)(outh + (size_t)d * F + c4) = sh;
        *(short4v*)(outl + (size_t)d * F + c4) = sl;
      } else {
        *(float4*)(outf + (size_t)d * F + c4) = o;
      }
    }
  }
}

// ---------------------------------------------------------------------------
extern "C" void kernel_launch(void* const* d_in, const int* in_sizes, int n_in,
                              void* d_out, int out_size, void* d_ws, size_t ws_size,
                              hipStream_t stream) {
  const float* x   = (const float*)d_in[0];
  const int* src0  = (const int*)d_in[1];
  const int* dst0  = (const int*)d_in[2];
  const int* src1  = (const int*)d_in[3];
  const int* dst1  = (const int*)d_in[4];
  const int* src2  = (const int*)d_in[5];
  const int* dst2  = (const int*)d_in[6];
  const float* W0  = (const float*)d_in[7];
  const float* al0 = (const float*)d_in[8];
  const float* ar0 = (const float*)d_in[9];
  const float* W1  = (const float*)d_in[10];
  const float* al1 = (const float*)d_in[11];
  const float* ar1 = (const float*)d_in[12];
  const float* W2  = (const float*)d_in[13];
  const float* al2 = (const float*)d_in[14];
  const float* ar2 = (const float*)d_in[15];

  const int N0 = 200000, N1 = 100000, N2 = 50000, N3 = 25000;
  const int E0 = in_sizes[1], E1 = in_sizes[3], E2 = in_sizes[5];
  const int Fin = 256, F = 192, C = 40;

  // ---- workspace layout ----
  float* ws     = (float*)d_ws;
  float* h_buf  = ws;                          // 200000*192 fp32 (gemm C)
  float* el_buf = h_buf + (size_t)N0 * F;      // 200000*4 (stride-4 padded)
  float* er_buf = el_buf + (size_t)N0 * 4;     // 100000*4
  short* o_hi   = (short*)(er_buf + (size_t)N1 * 4);  // 100000*192 bf16 planes
  short* o_lo   = o_hi + (size_t)N1 * F;
  short* w0h    = o_lo + (size_t)N1 * F;
  short* w0l    = w0h + 192 * 256;
  short* w1h    = w0l + 192 * 256;
  short* w1l    = w1h + 192 * 192;
  short* w2h    = w1l + 192 * 192;
  short* w2l    = w2h + 40 * 192;
  int*   off0   = (int*)(w2l + 40 * 192);
  int*   off1   = off0 + (N1 + 1);
  int*   off2   = off1 + (N2 + 1);

  dim3 blk(256);

  // ---- pre-passes ----
  const int WTOT = 256 * 192 + 192 * 192 + 192 * 40;
  conv_w_all<<<dim3((WTOT + 255) / 256), blk, 0, stream>>>(W0, W1, W2, w0h, w0l, w1h, w1l, w2h, w2l);
  const int ETOT = E0 + E1 + E2;
  csr_all<<<dim3((ETOT + 255) / 256), blk, 0, stream>>>(dst0, dst1, dst2, off0, off1, off2,
                                                        E0, E1, E2, N1, N2, N3);

  // ---- Layer 0 (A = x fp32, inline split) ----
  gemm_fused<12, 3, 4, false><<<dim3((N0 + 127) / 128), blk, 0, stream>>>(
      x, nullptr, nullptr, w0h, w0l, al0, ar0, h_buf, el_buf, er_buf, N0, F, Fin, N1);
  agg3_kernel<3, 64, 4, true, true><<<dim3((N1 + 15) / 16), blk, 0, stream>>>(
      h_buf, el_buf, er_buf, src0, off0, nullptr, o_hi, o_lo, N1);

  // ---- Layer 1 (A = pre-split planes) ----
  gemm_fused<12, 3, 4, true><<<dim3((N1 + 127) / 128), blk, 0, stream>>>(
      nullptr, o_hi, o_lo, w1h, w1l, al1, ar1, h_buf, el_buf, er_buf, N1, F, F, N2);
  agg3_kernel<3, 64, 4, true, true><<<dim3((N2 + 15) / 16), blk, 0, stream>>>(
      h_buf, el_buf, er_buf, src1, off1, nullptr, o_hi, o_lo, N2);

  // ---- Layer 2 (N=40, H=1, pre-split A, fp32 out, no relu) ----
  gemm_fused<3, 1, 1, true><<<dim3((N2 + 127) / 128), blk, 0, stream>>>(
      nullptr, o_hi, o_lo, w2h, w2l, al2, ar2, h_buf, el_buf, er_buf, N2, C, F, N3);
  agg3_kernel<1, 40, 1, false, false><<<dim3((N3 + 15) / 16), blk, 0, stream>>>(
      h_buf, el_buf, er_buf, src2, off2, (float*)d_out, nullptr, nullptr, N3);
}